// Round 11
// baseline (261.776 us; speedup 1.0000x reference)
//
#include <hip/hip_runtime.h>
#include <hip/hip_bf16.h>

#define B_  8
#define N_  2048
#define KD_ 256
#define AD_ 128
#define VD_ 256
#define SQL2E 1.2011224087864498f   // sqrt(log2(e)); folded into proj so attn uses exp2

using s16x8 = __attribute__((ext_vector_type(8))) short;
using f16x8 = __attribute__((ext_vector_type(8))) _Float16;
using h2    = __attribute__((ext_vector_type(2))) __fp16;
using f32x4 = __attribute__((ext_vector_type(4))) float;

__device__ __forceinline__ f32x4 mfma16(s16x8 a, s16x8 b, f32x4 c) {
  return __builtin_amdgcn_mfma_f32_16x16x32_f16(
      __builtin_bit_cast(f16x8, a), __builtin_bit_cast(f16x8, b), c, 0, 0, 0);
}
__device__ __forceinline__ short f2h(float f) {
  _Float16 h = (_Float16)f;
  return *reinterpret_cast<short*>(&h);
}
// raw hardware exp2 (v_exp_f32): 1 VALU op (libm exp2f = OCML precise path,
// ~6-8 ops -- measured regression R6/R7).
__device__ __forceinline__ float exp2_hw(float x) {
#if __has_builtin(__builtin_amdgcn_exp2f)
  return __builtin_amdgcn_exp2f(x);
#else
  float r;
  asm volatile("v_exp_f32 %0, %1" : "=v"(r) : "v"(x));
  return r;
#endif
}
__device__ __forceinline__ s16x8 cvt8(const float* __restrict__ p) {
  union { s16x8 v; h2 h[4]; } u;
  f32x4 a = *(const f32x4*)p;
  f32x4 bq = *(const f32x4*)(p + 4);
  u.h[0] = __builtin_amdgcn_cvt_pkrtz(a[0], a[1]);
  u.h[1] = __builtin_amdgcn_cvt_pkrtz(a[2], a[3]);
  u.h[2] = __builtin_amdgcn_cvt_pkrtz(bq[0], bq[1]);
  u.h[3] = __builtin_amdgcn_cvt_pkrtz(bq[2], bq[3]);
  return u.v;
}

// ---------------- fused prep (unchanged from R8) ----------------------------
__global__ __launch_bounds__(256) void prep_k(
    const float* __restrict__ k1, const float* __restrict__ k2,
    const float* __restrict__ v1, const float* __restrict__ v2,
    const float* __restrict__ W1, const float* __restrict__ b1f,
    const float* __restrict__ W2, const float* __restrict__ b2f,
    short* __restrict__ q1p, short* __restrict__ q2p,
    short* __restrict__ vt1, short* __restrict__ vt2) {
  __shared__ __align__(16) short sWT[128 * 264];   // proj role only
  const int t  = threadIdx.x;
  const int id = blockIdx.x;

  if (id < 512) {
    const int kt = id & 31, b = (id >> 5) & 7, z = id >> 8;
    const float* src = z ? v2 : v1;
    short*       dst = z ? vt2 : vt1;
    const size_t base = ((size_t)(b * 32 + kt)) * (256 * 64);
    const int w = t >> 6, vchunk = (t >> 4) & 3, l16 = t & 15;
    #pragma unroll
    for (int i = 0; i < 8; i++) {
      float x[8];
      #pragma unroll
      for (int kk = 0; kk < 8; kk++)
        x[kk] = src[((size_t)(b * N_ + kt * 64 + i * 8 + kk)) * VD_ + t];
      union { s16x8 v; h2 h[4]; } u;
      #pragma unroll
      for (int kk = 0; kk < 4; kk++)
        u.h[kk] = __builtin_amdgcn_cvt_pkrtz(x[2 * kk], x[2 * kk + 1]);
      int f = vchunk * 2 + (i >> 2);
      *(s16x8*)&dst[base + (size_t)((w * 8 + f) * 64 + (i & 3) * 16 + l16) * 8] = u.v;
    }
    return;
  }

  const int pid = id - 512;
  const int z = pid >> 8, mb = pid & 255;
  const float* X    = z ? k2 : k1;
  const float* W    = z ? W2 : W1;
  const float* bias = z ? b2f : b1f;
  short*       Y    = z ? q2p : q1p;
  const int m0   = mb * 64;
  const int lane = t & 63, wave = t >> 6, quad = lane >> 4, l16 = lane & 15;

  #pragma unroll
  for (int j = 0; j < 64; j++) {
    int idx = j * 256 + t;
    int n = idx & 127, kh = idx >> 7;
    h2 p = __builtin_amdgcn_cvt_pkrtz(W[(size_t)(2 * kh) * AD_ + n] * SQL2E,
                                      W[(size_t)(2 * kh + 1) * AD_ + n] * SQL2E);
    *(h2*)&sWT[n * 264 + kh * 2] = p;
  }
  const float* xrow = &X[(size_t)(m0 + wave * 16 + l16) * KD_];
  s16x8 a[8];
  #pragma unroll
  for (int ks = 0; ks < 8; ks++) a[ks] = cvt8(xrow + ks * 32 + quad * 8);
  __syncthreads();

  f32x4 acc[8];
  #pragma unroll
  for (int nt = 0; nt < 8; nt++) acc[nt] = (f32x4){0.f, 0.f, 0.f, 0.f};
  #pragma unroll
  for (int ks = 0; ks < 8; ks++) {
    #pragma unroll
    for (int nt = 0; nt < 8; nt++) {
      s16x8 bf = *(const s16x8*)&sWT[(nt * 16 + l16) * 264 + ks * 32 + quad * 8];
      acc[nt] = mfma16(a[ks], bf, acc[nt]);
    }
  }
  #pragma unroll
  for (int nt = 0; nt < 8; nt++) {
    float bv = bias[nt * 16 + l16] * SQL2E;
    #pragma unroll
    for (int r = 0; r < 4; r++) {
      int row = m0 + wave * 16 + quad * 4 + r;
      Y[(size_t)row * AD_ + nt * 16 + l16] = f2h(acc[nt][r] + bv);
    }
  }
}

// ---------------- flash attention: 8-wave blocks, reg-K, no sK --------------
// 512 threads, 64 q-rows/block. Wave w = (qh = w&1, kq = w>>1):
//   QK: keys [kq*16,+16) x q [qh*32,+32) -- kf (4 s16x8) from L2-hot global,
//       pure-register MFMA (8/iter).
//   PV: v-split 8 ways: all 64 q x v-cols [w*32,+32) -- pv from global, P via
//       sP (XOR-swizzled), 16 MFMA/iter, ONE WINDOW BEHIND (R10 pipeline).
// Softmax: quarter-max publish pre-barrier (sMt), unify post-barrier;
// defer-max decision uniform across the kq quartet; per-row alpha table
// always written. One barrier/iter. __launch_bounds__(512,4): VGPR<=128 ->
// 2 blocks/CU = 16 waves/CU (2x R10 TLP).
__global__ __launch_bounds__(512, 4) void attn_k(
    const short* __restrict__ q1p, const short* __restrict__ q2p,
    const short* __restrict__ vt1, const short* __restrict__ vt2,
    float* __restrict__ out) {
  __shared__ __align__(16) short sP[2][64 * 64];      // 16384 B, XOR-swizzled
  __shared__ __align__(16) float sMt[2][2][2][4][16]; // [c][qh][qt][kq][l16] 2KB
  __shared__ __align__(16) float sAl[2][64];          // alpha per q-row (or 1)
  __shared__ __align__(16) float sFl[2][2];           // rescale flag per qh
  __shared__ __align__(16) float sL[64];              // epilogue 1/l

  const int t    = threadIdx.x;
  const int lane = t & 63, w = t >> 6, quad = lane >> 4, l16 = lane & 15;
  const int qh   = w & 1, kq = w >> 1;
  const int id   = blockIdx.x;
  const int xcd  = id & 7, seq = id >> 3;
  const int bp   = xcd * 2 + (seq >> 5);
  const int qb   = seq & 31;
  const int b    = bp & 7, pass = bp >> 3;
  const int q0   = qb * 64;
  const short* Q  = pass ? q2p : q1p;
  const short* K  = pass ? q1p : q2p;
  const short* Vt = pass ? vt1 : vt2;
  float* O = out + (size_t)pass * ((size_t)B_ * N_ * VD_);

  // K quarter: key row kq*16 + l16, d-chunk quad*8 (A-frag from global)
  const short* kp = K + ((size_t)(b * N_) + kq * 16 + l16) * AD_ + quad * 8;
  // V slice: cols [w*32,+32): pv[g = v*2+ks2] at vp + g*512
  const short* vp = Vt + (size_t)b * 32 * (256 * 64) + w * 2048 + lane * 8;

  // Q fragments (loop-invariant, 32 VGPR): qf[qt][ks], q = qh*32+qt*16+l16
  s16x8 qf[2][4];
  #pragma unroll
  for (int qt = 0; qt < 2; qt++)
    #pragma unroll
    for (int ks = 0; ks < 4; ks++)
      qf[qt][ks] = *(const s16x8*)&Q[((size_t)(b * N_ + q0 + qh * 32 + qt * 16 +
                                               l16)) * AD_ + ks * 32 + quad * 8];

  float m2[2] = {-1e30f, -1e30f};   // running max per qt (log2 domain)
  float l2[2] = {0.f, 0.f};         // partial l per qt
  f32x4 acc[8];                     // [m*2+v]: q-16tile m x v-16tile v
  #pragma unroll
  for (int c0 = 0; c0 < 8; c0++) acc[c0] = (f32x4){0.f, 0.f, 0.f, 0.f};

  s16x8 kf[4], pv[4];
  auto loadK = [&]() {
    #pragma unroll
    for (int ks = 0; ks < 4; ks++) kf[ks] = *(const s16x8*)(kp + ks * 32);
    kp += 64 * AD_;
  };
  auto loadV = [&]() {
    #pragma unroll
    for (int g = 0; g < 4; g++) pv[g] = *(const s16x8*)(vp + g * 512);
    vp += 256 * 64;
  };

  loadK();   // kf <- K(0)
  loadV();   // pv <- V(0)

  f32x4 stq[2];

  for (int i = 0; i <= 32; i++) {
    const int c = i & 1;
    if (i < 32) {
      // QK(i): S^T[key = kq*16+quad*4+r][q = qh*32+qt*16+l16], pure registers
      stq[0] = (f32x4){0.f, 0.f, 0.f, 0.f};
      stq[1] = (f32x4){0.f, 0.f, 0.f, 0.f};
      __builtin_amdgcn_s_setprio(1);
      #pragma unroll
      for (int ks = 0; ks < 4; ks++) {
        stq[0] = mfma16(kf[ks], qf[0][ks], stq[0]);
        stq[1] = mfma16(kf[ks], qf[1][ks], stq[1]);
      }
      __builtin_amdgcn_s_setprio(0);

      // quarter max per qt: in-lane 4 + cross-quad combine; publish
      float hm0 = fmaxf(fmaxf(stq[0][0], stq[0][1]), fmaxf(stq[0][2], stq[0][3]));
      float hm1 = fmaxf(fmaxf(stq[1][0], stq[1][1]), fmaxf(stq[1][2], stq[1][3]));
      hm0 = fmaxf(hm0, __shfl_xor(hm0, 16)); hm0 = fmaxf(hm0, __shfl_xor(hm0, 32));
      hm1 = fmaxf(hm1, __shfl_xor(hm1, 16)); hm1 = fmaxf(hm1, __shfl_xor(hm1, 32));
      if (quad == 0) {
        sMt[c][qh][0][kq][l16] = hm0;
        sMt[c][qh][1][kq][l16] = hm1;
      }
    }

    __syncthreads();
    if (i + 1 < 32) loadK();           // kf <- K(i+1); drains next window

    if (i > 0) {
      const int cprev = 1 - c;
      // rescale acc by alpha(i-1) if any qh group rescaled (rare)
      if (sFl[cprev][0] + sFl[cprev][1] != 0.f) {
        #pragma unroll
        for (int m = 0; m < 4; m++) {
          f32x4 aR = *(const f32x4*)&sAl[cprev][m * 16 + quad * 4];
          #pragma unroll
          for (int v = 0; v < 2; v++) {
            #pragma unroll
            for (int r = 0; r < 4; r++) acc[m * 2 + v][r] *= aR[r];
          }
        }
      }
      // PV(i-1): af from sP[cprev]; V in registers
      __builtin_amdgcn_s_setprio(1);
      #pragma unroll
      for (int m = 0; m < 4; m++) {
        #pragma unroll
        for (int ks2 = 0; ks2 < 2; ks2++) {
          int physr = (ks2 * 8 + quad * 2) ^ ((l16 & 7) << 1);
          s16x8 af = *(const s16x8*)&sP[cprev][(m * 16 + l16) * 64 + physr * 4];
          #pragma unroll
          for (int v = 0; v < 2; v++)
            acc[m * 2 + v] = mfma16(af, pv[v * 2 + ks2], acc[m * 2 + v]);
        }
      }
      __builtin_amdgcn_s_setprio(0);
      if (i < 32) loadV();             // pv <- V(i) for PV(i) next window
    }

    if (i < 32) {
      // unified tile max over the 4 key-quarters (identical across kq quartet)
      float mt0 = fmaxf(fmaxf(sMt[c][qh][0][0][l16], sMt[c][qh][0][1][l16]),
                        fmaxf(sMt[c][qh][0][2][l16], sMt[c][qh][0][3][l16]));
      float mt1 = fmaxf(fmaxf(sMt[c][qh][1][0][l16], sMt[c][qh][1][1][l16]),
                        fmaxf(sMt[c][qh][1][2][l16], sMt[c][qh][1][3][l16]));

      // defer-max (log2 units, P <= 2^8); uniform across the kq quartet
      bool ok   = (mt0 - m2[0] <= 8.f) && (mt1 - m2[1] <= 8.f);
      bool resc = !__all(ok);
      float al0 = 1.f, al1 = 1.f;
      if (resc) {
        float mn0 = fmaxf(m2[0], mt0), mn1 = fmaxf(m2[1], mt1);
        al0 = exp2_hw(m2[0] - mn0);  al1 = exp2_hw(m2[1] - mn1);
        m2[0] = mn0;  m2[1] = mn1;
        l2[0] *= al0; l2[1] *= al1;
      }
      if (kq == 0 && quad == 0) {
        sAl[c][qh * 32 + l16]      = al0;
        sAl[c][qh * 32 + 16 + l16] = al1;
      }
      if (kq == 0 && lane == 0) sFl[c][qh] = resc ? 1.f : 0.f;

      // exps + partial sums + pack -> sP[c] (consumed next window)
      #pragma unroll
      for (int qt = 0; qt < 2; qt++) {
        float mi = qt ? m2[1] : m2[0];
        float p0 = exp2_hw(stq[qt][0] - mi);
        float p1 = exp2_hw(stq[qt][1] - mi);
        float p2 = exp2_hw(stq[qt][2] - mi);
        float p3 = exp2_hw(stq[qt][3] - mi);
        l2[qt] += (p0 + p1) + (p2 + p3);
        union { h2 h[2]; uint2 u; } wu;
        wu.h[0] = __builtin_amdgcn_cvt_pkrtz(p0, p1);
        wu.h[1] = __builtin_amdgcn_cvt_pkrtz(p2, p3);
        int phys = (kq * 4 + quad) ^ ((l16 & 7) << 1);
        *(uint2*)&sP[c][(qh * 32 + qt * 16 + l16) * 64 + phys * 4] = wu.u;
      }
    }
  }

  // epilogue: l over quads -> publish -> sum over kq -> 1/l -> O
  l2[0] += __shfl_xor(l2[0], 16); l2[0] += __shfl_xor(l2[0], 32);
  l2[1] += __shfl_xor(l2[1], 16); l2[1] += __shfl_xor(l2[1], 32);
  if (quad == 0) {
    sMt[0][qh][0][kq][l16] = l2[0];
    sMt[0][qh][1][kq][l16] = l2[1];
  }
  __syncthreads();
  if (w < 4 && quad == 0) {
    int eh = w & 1, et = w >> 1;
    float s = sMt[0][eh][et][0][l16] + sMt[0][eh][et][1][l16] +
              sMt[0][eh][et][2][l16] + sMt[0][eh][et][3][l16];
    sL[eh * 32 + et * 16 + l16] = 1.f / s;
  }
  __syncthreads();
  #pragma unroll
  for (int m = 0; m < 4; m++) {
    f32x4 lv = *(const f32x4*)&sL[m * 16 + quad * 4];
    #pragma unroll
    for (int r = 0; r < 4; r++) {
      int row = q0 + m * 16 + quad * 4 + r;
      #pragma unroll
      for (int v = 0; v < 2; v++)
        O[((size_t)(b * N_ + row)) * VD_ + w * 32 + v * 16 + l16] =
            acc[m * 2 + v][r] * lv[r];
    }
  }
}

extern "C" void kernel_launch(void* const* d_in, const int* in_sizes, int n_in,
                              void* d_out, int out_size, void* d_ws, size_t ws_size,
                              hipStream_t stream) {
  const float* k1 = (const float*)d_in[0];
  const float* k2 = (const float*)d_in[1];
  const float* v1 = (const float*)d_in[2];
  const float* v2 = (const float*)d_in[3];
  const float* W1 = (const float*)d_in[4];
  const float* b1 = (const float*)d_in[5];
  const float* W2 = (const float*)d_in[6];
  const float* b2 = (const float*)d_in[7];

  short* ws  = (short*)d_ws;
  short* q1p = ws;                                   // 16384*128 f16 (4 MB)
  short* q2p = q1p + (size_t)16384 * 128;
  short* vt1 = q2p + (size_t)16384 * 128;            // 8*32*256*64 f16 (8.4 MB)
  short* vt2 = vt1 + (size_t)B_ * 32 * 256 * 64;
  float* out = (float*)d_out;

  prep_k<<<dim3(1024), dim3(256), 0, stream>>>(k1, k2, v1, v2, W1, b1, W2, b2,
                                               q1p, q2p, vt1, vt2);
  attn_k<<<dim3(512), dim3(512), 0, stream>>>(q1p, q2p, vt1, vt2, out);
}

// Round 12
// 236.211 us; speedup vs baseline: 1.1082x; 1.1082x over previous
//
#include <hip/hip_runtime.h>
#include <hip/hip_bf16.h>

#define B_  8
#define N_  2048
#define KD_ 256
#define AD_ 128
#define VD_ 256
#define SQL2E 1.2011224087864498f   // sqrt(log2(e)); folded into proj so attn uses exp2

using s16x8 = __attribute__((ext_vector_type(8))) short;
using f16x8 = __attribute__((ext_vector_type(8))) _Float16;
using h2    = __attribute__((ext_vector_type(2))) __fp16;
using f32x4 = __attribute__((ext_vector_type(4))) float;

__device__ __forceinline__ f32x4 mfma16(s16x8 a, s16x8 b, f32x4 c) {
  return __builtin_amdgcn_mfma_f32_16x16x32_f16(
      __builtin_bit_cast(f16x8, a), __builtin_bit_cast(f16x8, b), c, 0, 0, 0);
}
__device__ __forceinline__ short f2h(float f) {
  _Float16 h = (_Float16)f;
  return *reinterpret_cast<short*>(&h);
}
// raw hardware exp2 (v_exp_f32): 1 VALU op (libm exp2f = OCML precise path,
// ~6-8 ops -- measured regression R6/R7).
__device__ __forceinline__ float exp2_hw(float x) {
#if __has_builtin(__builtin_amdgcn_exp2f)
  return __builtin_amdgcn_exp2f(x);
#else
  float r;
  asm volatile("v_exp_f32 %0, %1" : "=v"(r) : "v"(x));
  return r;
#endif
}
__device__ __forceinline__ s16x8 cvt8(const float* __restrict__ p) {
  union { s16x8 v; h2 h[4]; } u;
  f32x4 a = *(const f32x4*)p;
  f32x4 bq = *(const f32x4*)(p + 4);
  u.h[0] = __builtin_amdgcn_cvt_pkrtz(a[0], a[1]);
  u.h[1] = __builtin_amdgcn_cvt_pkrtz(a[2], a[3]);
  u.h[2] = __builtin_amdgcn_cvt_pkrtz(bq[0], bq[1]);
  u.h[3] = __builtin_amdgcn_cvt_pkrtz(bq[2], bq[3]);
  return u.v;
}

// ---------------- fused prep (unchanged from R8) ----------------------------
__global__ __launch_bounds__(256) void prep_k(
    const float* __restrict__ k1, const float* __restrict__ k2,
    const float* __restrict__ v1, const float* __restrict__ v2,
    const float* __restrict__ W1, const float* __restrict__ b1f,
    const float* __restrict__ W2, const float* __restrict__ b2f,
    short* __restrict__ q1p, short* __restrict__ q2p,
    short* __restrict__ vt1, short* __restrict__ vt2) {
  __shared__ __align__(16) short sWT[128 * 264];   // proj role only
  const int t  = threadIdx.x;
  const int id = blockIdx.x;

  if (id < 512) {
    const int kt = id & 31, b = (id >> 5) & 7, z = id >> 8;
    const float* src = z ? v2 : v1;
    short*       dst = z ? vt2 : vt1;
    const size_t base = ((size_t)(b * 32 + kt)) * (256 * 64);
    const int w = t >> 6, vchunk = (t >> 4) & 3, l16 = t & 15;
    #pragma unroll
    for (int i = 0; i < 8; i++) {
      float x[8];
      #pragma unroll
      for (int kk = 0; kk < 8; kk++)
        x[kk] = src[((size_t)(b * N_ + kt * 64 + i * 8 + kk)) * VD_ + t];
      union { s16x8 v; h2 h[4]; } u;
      #pragma unroll
      for (int kk = 0; kk < 4; kk++)
        u.h[kk] = __builtin_amdgcn_cvt_pkrtz(x[2 * kk], x[2 * kk + 1]);
      int f = vchunk * 2 + (i >> 2);
      *(s16x8*)&dst[base + (size_t)((w * 8 + f) * 64 + (i & 3) * 16 + l16) * 8] = u.v;
    }
    return;
  }

  const int pid = id - 512;
  const int z = pid >> 8, mb = pid & 255;
  const float* X    = z ? k2 : k1;
  const float* W    = z ? W2 : W1;
  const float* bias = z ? b2f : b1f;
  short*       Y    = z ? q2p : q1p;
  const int m0   = mb * 64;
  const int lane = t & 63, wave = t >> 6, quad = lane >> 4, l16 = lane & 15;

  #pragma unroll
  for (int j = 0; j < 64; j++) {
    int idx = j * 256 + t;
    int n = idx & 127, kh = idx >> 7;
    h2 p = __builtin_amdgcn_cvt_pkrtz(W[(size_t)(2 * kh) * AD_ + n] * SQL2E,
                                      W[(size_t)(2 * kh + 1) * AD_ + n] * SQL2E);
    *(h2*)&sWT[n * 264 + kh * 2] = p;
  }
  const float* xrow = &X[(size_t)(m0 + wave * 16 + l16) * KD_];
  s16x8 a[8];
  #pragma unroll
  for (int ks = 0; ks < 8; ks++) a[ks] = cvt8(xrow + ks * 32 + quad * 8);
  __syncthreads();

  f32x4 acc[8];
  #pragma unroll
  for (int nt = 0; nt < 8; nt++) acc[nt] = (f32x4){0.f, 0.f, 0.f, 0.f};
  #pragma unroll
  for (int ks = 0; ks < 8; ks++) {
    #pragma unroll
    for (int nt = 0; nt < 8; nt++) {
      s16x8 bf = *(const s16x8*)&sWT[(nt * 16 + l16) * 264 + ks * 32 + quad * 8];
      acc[nt] = mfma16(a[ks], bf, acc[nt]);
    }
  }
  #pragma unroll
  for (int nt = 0; nt < 8; nt++) {
    float bv = bias[nt * 16 + l16] * SQL2E;
    #pragma unroll
    for (int r = 0; r < 4; r++) {
      int row = m0 + wave * 16 + quad * 4 + r;
      Y[(size_t)row * AD_ + nt * 16 + l16] = f2h(acc[nt][r] + bv);
    }
  }
}

// ---------------- flash attention: q32, reg-K/reg-V, 4 blocks/CU ------------
// 1024 blocks (32 q-rows each) -> exactly 4 blocks/CU, 16 waves/CU (2x R10).
// Wave w (=kq) owns keys [w*16,+16) of each tile (kf, regs, from L2-hot
// global) x all 32 q  -> QK pure-register, 8 MFMA. PV v-split: wave w covers
// all 32 q x v-cols [w*64,+64), in TWO v-halves with pv[4] reloaded mid-PV.
// P via sP (XOR-swizzled); PV one window behind; one barrier/iter.
// Softmax max unified via sMt (publish pre-barrier, read post-barrier);
// defer-max decision uniform across waves; per-row alpha via sAl (rare).
__global__ __launch_bounds__(256, 2) void attn_k(
    const short* __restrict__ q1p, const short* __restrict__ q2p,
    const short* __restrict__ vt1, const short* __restrict__ vt2,
    float* __restrict__ out) {
  __shared__ __align__(16) short sP[2][32 * 64];    // 8192 B, XOR-swizzled
  __shared__ __align__(16) float sMt[2][2][4][16];  // [c][qt][kq][l16] 1 KB
  __shared__ __align__(16) float sAl[2][32];        // alpha per q-row (resc)
  __shared__ __align__(16) float sL[32];            // epilogue 1/l

  const int t    = threadIdx.x;
  const int lane = t & 63, w = t >> 6, quad = lane >> 4, l16 = lane & 15;
  const int kq   = w;                                // key-quarter == wave
  const int id   = blockIdx.x;
  const int xcd  = id & 7, seq = id >> 3;            // 1024 % 8 == 0: bijective
  const int bp   = xcd * 2 + (seq >> 6);
  const int qb   = seq & 63;
  const int b    = bp & 7, pass = bp >> 3;
  const int q0   = qb * 32;
  const short* Q  = pass ? q2p : q1p;
  const short* K  = pass ? q1p : q2p;
  const short* Vt = pass ? vt1 : vt2;
  float* O = out + (size_t)pass * ((size_t)B_ * N_ * VD_);

  // K quarter: key row kq*16 + l16, d-chunk quad*8 (A-frag direct from global)
  const short* kp = K + ((size_t)(b * N_) + kq * 16 + l16) * AD_ + quad * 8;
  // V slice: col-group w (64 cols); frag f at vp + f*512
  const short* vp = Vt + (size_t)b * 32 * (256 * 64) + w * 4096 + lane * 8;

  // Q fragments (loop-invariant): qf[qt][ks], q-row = q0 + qt*16 + l16
  s16x8 qf[2][4];
  #pragma unroll
  for (int qt = 0; qt < 2; qt++)
    #pragma unroll
    for (int ks = 0; ks < 4; ks++)
      qf[qt][ks] = *(const s16x8*)&Q[((size_t)(b * N_ + q0 + qt * 16 + l16)) * AD_ +
                                     ks * 32 + quad * 8];

  float m2[2] = {-1e30f, -1e30f};   // running max per qt (log2), per q-row l16
  float l2[2] = {0.f, 0.f};         // partial l per qt
  f32x4 acc[8];                     // [m*4+v]: q-16tile m x v-16tile v (0..3)
  #pragma unroll
  for (int c0 = 0; c0 < 8; c0++) acc[c0] = (f32x4){0.f, 0.f, 0.f, 0.f};

  s16x8 kf[4], pv[4];
  auto loadK = [&]() {
    #pragma unroll
    for (int ks = 0; ks < 4; ks++) kf[ks] = *(const s16x8*)(kp + ks * 32);
    kp += 64 * AD_;
  };

  loadK();                                           // kf <- K(0)
  #pragma unroll
  for (int g = 0; g < 4; g++) pv[g] = *(const s16x8*)(vp + g * 512);  // A(0)

  f32x4 stq[2];
  bool prevResc = false;

  for (int i = 0; i <= 32; i++) {
    const int c = i & 1;
    if (i < 32) {
      // QK(i): S^T[key = kq*16+quad*4+r][q = qt*16+l16], pure registers
      stq[0] = (f32x4){0.f, 0.f, 0.f, 0.f};
      stq[1] = (f32x4){0.f, 0.f, 0.f, 0.f};
      __builtin_amdgcn_s_setprio(1);
      #pragma unroll
      for (int ks = 0; ks < 4; ks++) {
        stq[0] = mfma16(kf[ks], qf[0][ks], stq[0]);
        stq[1] = mfma16(kf[ks], qf[1][ks], stq[1]);
      }
      __builtin_amdgcn_s_setprio(0);

      // quarter max per qt (in-lane 4 + cross-quad) -> publish
      float hm0 = fmaxf(fmaxf(stq[0][0], stq[0][1]), fmaxf(stq[0][2], stq[0][3]));
      float hm1 = fmaxf(fmaxf(stq[1][0], stq[1][1]), fmaxf(stq[1][2], stq[1][3]));
      hm0 = fmaxf(hm0, __shfl_xor(hm0, 16)); hm0 = fmaxf(hm0, __shfl_xor(hm0, 32));
      hm1 = fmaxf(hm1, __shfl_xor(hm1, 16)); hm1 = fmaxf(hm1, __shfl_xor(hm1, 32));
      if (quad == 0) {
        sMt[c][0][kq][l16] = hm0;
        sMt[c][1][kq][l16] = hm1;
      }
    }

    __syncthreads();
    if (i + 1 < 32) loadK();           // kf <- K(i+1); consumed next window

    if (i > 0) {
      const int cprev = 1 - c;
      // rescale acc by alpha(i-1) (rare; decision uniform, kept in reg)
      if (prevResc) {
        #pragma unroll
        for (int m = 0; m < 2; m++) {
          f32x4 aR = *(const f32x4*)&sAl[cprev][m * 16 + quad * 4];
          #pragma unroll
          for (int v = 0; v < 4; v++) {
            #pragma unroll
            for (int r = 0; r < 4; r++) acc[m * 4 + v][r] *= aR[r];
          }
        }
      }
      // PV(i-1) half A (v-tiles 0,1): pv = A(i-1) loaded last window
      __builtin_amdgcn_s_setprio(1);
      #pragma unroll
      for (int m = 0; m < 2; m++) {
        #pragma unroll
        for (int ks2 = 0; ks2 < 2; ks2++) {
          int physr = (ks2 * 8 + quad * 2) ^ ((l16 & 7) << 1);
          s16x8 af = *(const s16x8*)&sP[cprev][(m * 16 + l16) * 64 + physr * 4];
          #pragma unroll
          for (int v = 0; v < 2; v++)
            acc[m * 4 + v] = mfma16(af, pv[v * 2 + ks2], acc[m * 4 + v]);
        }
      }
      __builtin_amdgcn_s_setprio(0);
      // load half B of V(i-1) into pv
      #pragma unroll
      for (int g = 0; g < 4; g++) pv[g] = *(const s16x8*)(vp + (4 + g) * 512);
      // PV(i-1) half B (v-tiles 2,3)
      __builtin_amdgcn_s_setprio(1);
      #pragma unroll
      for (int m = 0; m < 2; m++) {
        #pragma unroll
        for (int ks2 = 0; ks2 < 2; ks2++) {
          int physr = (ks2 * 8 + quad * 2) ^ ((l16 & 7) << 1);
          s16x8 af = *(const s16x8*)&sP[cprev][(m * 16 + l16) * 64 + physr * 4];
          #pragma unroll
          for (int v = 0; v < 2; v++)
            acc[m * 4 + 2 + v] = mfma16(af, pv[v * 2 + ks2], acc[m * 4 + 2 + v]);
        }
      }
      __builtin_amdgcn_s_setprio(0);
      vp += 256 * 64;                  // advance to tile i
      if (i < 32) {                    // pv <- A(i) for next window
        #pragma unroll
        for (int g = 0; g < 4; g++) pv[g] = *(const s16x8*)(vp + g * 512);
      }
    }

    if (i < 32) {
      // unified tile max over the 4 key-quarters (identical on all waves)
      float mt0 = fmaxf(fmaxf(sMt[c][0][0][l16], sMt[c][0][1][l16]),
                        fmaxf(sMt[c][0][2][l16], sMt[c][0][3][l16]));
      float mt1 = fmaxf(fmaxf(sMt[c][1][0][l16], sMt[c][1][1][l16]),
                        fmaxf(sMt[c][1][2][l16], sMt[c][1][3][l16]));

      // defer-max (log2 units, P <= 2^8); uniform across waves
      bool ok   = (mt0 - m2[0] <= 8.f) && (mt1 - m2[1] <= 8.f);
      bool resc = !__all(ok);
      if (resc) {
        float mn0 = fmaxf(m2[0], mt0), mn1 = fmaxf(m2[1], mt1);
        float al0 = exp2_hw(m2[0] - mn0), al1 = exp2_hw(m2[1] - mn1);
        m2[0] = mn0;  m2[1] = mn1;
        l2[0] *= al0; l2[1] *= al1;
        if (kq == 0 && quad == 0) {
          sAl[c][l16]      = al0;
          sAl[c][16 + l16] = al1;
        }
      }
      prevResc = resc;

      // exps + partial sums + pack -> sP[c] (consumed next window)
      #pragma unroll
      for (int qt = 0; qt < 2; qt++) {
        float mi = qt ? m2[1] : m2[0];
        float p0 = exp2_hw(stq[qt][0] - mi);
        float p1 = exp2_hw(stq[qt][1] - mi);
        float p2 = exp2_hw(stq[qt][2] - mi);
        float p3 = exp2_hw(stq[qt][3] - mi);
        l2[qt] += (p0 + p1) + (p2 + p3);
        union { h2 h[2]; uint2 u; } wu;
        wu.h[0] = __builtin_amdgcn_cvt_pkrtz(p0, p1);
        wu.h[1] = __builtin_amdgcn_cvt_pkrtz(p2, p3);
        int phys = (kq * 4 + quad) ^ ((l16 & 7) << 1);
        *(uint2*)&sP[c][(qt * 16 + l16) * 64 + phys * 4] = wu.u;
      }
    }
  }

  // epilogue: l over quads -> publish -> sum over kq -> 1/l -> O
  l2[0] += __shfl_xor(l2[0], 16); l2[0] += __shfl_xor(l2[0], 32);
  l2[1] += __shfl_xor(l2[1], 16); l2[1] += __shfl_xor(l2[1], 32);
  if (quad == 0) {
    sMt[0][0][kq][l16] = l2[0];
    sMt[0][1][kq][l16] = l2[1];
  }
  __syncthreads();
  if (w == 0 && quad == 0) {
    float s0 = sMt[0][0][0][l16] + sMt[0][0][1][l16] +
               sMt[0][0][2][l16] + sMt[0][0][3][l16];
    float s1 = sMt[0][1][0][l16] + sMt[0][1][1][l16] +
               sMt[0][1][2][l16] + sMt[0][1][3][l16];
    sL[l16]      = 1.f / s0;
    sL[16 + l16] = 1.f / s1;
  }
  __syncthreads();
  #pragma unroll
  for (int m = 0; m < 2; m++) {
    f32x4 lv = *(const f32x4*)&sL[m * 16 + quad * 4];
    #pragma unroll
    for (int r = 0; r < 4; r++) {
      float inv = lv[r];
      int row = q0 + m * 16 + quad * 4 + r;
      #pragma unroll
      for (int v = 0; v < 4; v++)
        O[((size_t)(b * N_ + row)) * VD_ + w * 64 + v * 16 + l16] =
            acc[m * 4 + v][r] * inv;
    }
  }
}

extern "C" void kernel_launch(void* const* d_in, const int* in_sizes, int n_in,
                              void* d_out, int out_size, void* d_ws, size_t ws_size,
                              hipStream_t stream) {
  const float* k1 = (const float*)d_in[0];
  const float* k2 = (const float*)d_in[1];
  const float* v1 = (const float*)d_in[2];
  const float* v2 = (const float*)d_in[3];
  const float* W1 = (const float*)d_in[4];
  const float* b1 = (const float*)d_in[5];
  const float* W2 = (const float*)d_in[6];
  const float* b2 = (const float*)d_in[7];

  short* ws  = (short*)d_ws;
  short* q1p = ws;                                   // 16384*128 f16 (4 MB)
  short* q2p = q1p + (size_t)16384 * 128;
  short* vt1 = q2p + (size_t)16384 * 128;            // 8*32*256*64 f16 (8.4 MB)
  short* vt2 = vt1 + (size_t)B_ * 32 * 256 * 64;
  float* out = (float*)d_out;

  prep_k<<<dim3(1024), dim3(256), 0, stream>>>(k1, k2, v1, v2, W1, b1, W2, b2,
                                               q1p, q2p, vt1, vt2);
  attn_k<<<dim3(1024), dim3(256), 0, stream>>>(q1p, q2p, vt1, vt2, out);
}